// Round 4
// baseline (275.513 us; speedup 1.0000x reference)
//
#include <hip/hip_runtime.h>

// BondWeight: out[b, src+1, dst+1] = w; out[b, dst+1, src+1] = w (two passes,
// last-write-wins within the 1024-write per-batch sequence, numpy semantics).
// B=1024, E=512, T=8, N=256. Output 256 MB f32 -> pure HBM-write-bound (~42us).
//
// R4: one 64-row chunk per BLOCK (4096 blocks, 4 per batch) instead of a
// 4-chunk loop per block. Rationale: R2/R3's chunk loop ran all resident
// blocks in lockstep (zero->scatter->barrier->stream x4), idling the store
// pipe during every non-stream phase. Now each block does: load edges,
// zero 32KB table, one CAS-max scatter, ONE barrier, stream 64KB, exit.
// 16 block-rounds/CU retire asynchronously -> phases overlap across blocks.
// Each block reads all 512 edges of its batch (4x fetch = 48MB, L3-absorbed).

#define NB_E 512
#define NB_N 256
#define CH_ROWS 64
#define CH_WORDS (CH_ROWS * NB_N / 2)   // 8192 u32 = 32 KB LDS

typedef float v4f __attribute__((ext_vector_type(4)));

__device__ __forceinline__ void lds_max_u16(unsigned int* tab, int cell, unsigned int v16)
{
    unsigned int* w = tab + (cell >> 1);
    const int sh = (cell & 1) * 16;
    unsigned int old = *w;
    while (true) {
        const unsigned int cur = (old >> sh) & 0xFFFFu;
        if (cur >= v16) break;                       // current winner is later
        const unsigned int nw = (old & ~(0xFFFFu << sh)) | (v16 << sh);
        const unsigned int seen = atomicCAS(w, old, nw);
        if (seen == old) break;
        old = seen;                                  // contended: retry
    }
}

__global__ __launch_bounds__(256) void BondWeight_41738492182540_kernel(
    const float* __restrict__ weights,
    const int*   __restrict__ bsrc,
    const int*   __restrict__ bdst,
    const int*   __restrict__ btyp,
    float*       __restrict__ out)
{
    __shared__ unsigned int seqtab[CH_WORDS];
    __shared__ float s_wt[8];

    const int bx = blockIdx.x;
    const int b  = bx >> 2;                 // batch
    const int r0 = (bx & 3) * CH_ROWS;      // my 64-row window
    const int t  = threadIdx.x;

    if (t < 8) s_wt[t] = weights[t];

    // --- zero my chunk table: 8192 u32, uint4 x 8 per thread ---
    {
        uint4* tab4 = (uint4*)seqtab;
        #pragma unroll
        for (int k = 0; k < CH_WORDS / 4 / 256; ++k)
            tab4[t + 256 * k] = make_uint4(0u, 0u, 0u, 0u);
    }

    // --- load my 2 edges (int2, coalesced 8B/lane) -> 4 writes ---
    // seq order: pass1 (src,dst) e=0..511 then pass2 (dst,src) e=0..511.
    // packed = (seq+1)<<3 | type; CAS-max == reference last-write-wins.
    const int2 s2 = ((const int2*)(bsrc + b * NB_E))[t];
    const int2 d2 = ((const int2*)(bdst + b * NB_E))[t];
    const int2 y2 = ((const int2*)(btyp + b * NB_E))[t];

    int row[4], col[4];
    unsigned int pk[4];
    {
        const int e0 = 2 * t, e1 = 2 * t + 1;
        const int sa = s2.x + 1, da = d2.x + 1;          // [1,255]
        const int sb = s2.y + 1, db = d2.y + 1;
        const unsigned int ta = (unsigned int)y2.x & 7u;
        const unsigned int tb = (unsigned int)y2.y & 7u;
        row[0] = sa; col[0] = da; pk[0] = ((unsigned int)(e0 + 1) << 3) | ta;
        row[1] = sb; col[1] = db; pk[1] = ((unsigned int)(e1 + 1) << 3) | tb;
        row[2] = da; col[2] = sa; pk[2] = ((unsigned int)(NB_E + e0 + 1) << 3) | ta;
        row[3] = db; col[3] = sb; pk[3] = ((unsigned int)(NB_E + e1 + 1) << 3) | tb;
    }

    __syncthreads();    // table zeroed before any CAS

    // --- scatter the writes that land in my window ---
    #pragma unroll
    for (int i = 0; i < 4; ++i) {
        const int r = row[i] - r0;
        if (0 <= r && r < CH_ROWS)
            lds_max_u16(seqtab, r * NB_N + col[i], pk[i]);
    }

    __syncthreads();    // all CAS done before stream reads

    // --- stream my 64 rows: 4096 float4, 16/thread, fully coalesced ---
    float4* __restrict__ out4 = ((float4*)out)
        + (size_t)b * (NB_N * NB_N / 4) + r0 * (NB_N / 4);
    const uint2* __restrict__ tab2 = (const uint2*)seqtab;

    #pragma unroll
    for (int k = 0; k < (CH_ROWS * NB_N / 4) / 256; ++k) {
        const int i4 = t + 256 * k;
        const uint2 ab = tab2[i4];               // ds_read_b64
        v4f v;
        unsigned int p;
        p = ab.x & 0xFFFFu; v.x = p ? s_wt[p & 7u] : 0.0f;
        p = ab.x >> 16;     v.y = p ? s_wt[p & 7u] : 0.0f;
        p = ab.y & 0xFFFFu; v.z = p ? s_wt[p & 7u] : 0.0f;
        p = ab.y >> 16;     v.w = p ? s_wt[p & 7u] : 0.0f;
        *(v4f*)&out4[i4] = v;
    }
}

extern "C" void kernel_launch(void* const* d_in, const int* in_sizes, int n_in,
                              void* d_out, int out_size, void* d_ws, size_t ws_size,
                              hipStream_t stream) {
    const float* weights = (const float*)d_in[0];   // [T=8]
    const int*   bsrc    = (const int*)d_in[1];     // [B, E]
    const int*   bdst    = (const int*)d_in[2];     // [B, E]
    const int*   btyp    = (const int*)d_in[3];     // [B, E]
    float*       out     = (float*)d_out;           // [B, N, N] f32

    const int nb = in_sizes[1] / NB_E;              // B = 1024

    BondWeight_41738492182540_kernel<<<nb * 4, 256, 0, stream>>>(
        weights, bsrc, bdst, btyp, out);
}